// Round 9
// baseline (1404.327 us; speedup 1.0000x reference)
//
#include <hip/hip_runtime.h>
#include <stdint.h>

#define HD   128
#define ED   100
#define VD   1000
#define FDV  512
#define NS   512
#define TT   64
#define MT   (NS*TT)   // 32768

typedef __attribute__((ext_vector_type(8))) short  short8;
typedef __attribute__((ext_vector_type(4))) float  f32x4;

typedef const __attribute__((address_space(1))) uint16_t* gas_u16;
typedef __attribute__((address_space(3))) uint16_t*       las_u16;

__device__ __forceinline__ float blo(uint32_t u){ return __uint_as_float(u << 16); }
__device__ __forceinline__ float bhi(uint32_t u){ return __uint_as_float(u & 0xffff0000u); }
__device__ __forceinline__ uint16_t f2bf(float f){
  uint32_t x = __float_as_uint(f);
  return (uint16_t)((x + 0x7fffu + ((x >> 16) & 1u)) >> 16);
}
__device__ __forceinline__ float sigf(float x){ return 1.f/(1.f+__expf(-x)); }
__device__ __forceinline__ float ftanh(float x){
  float ax = fabsf(x);
  float e = __expf(-2.f*ax);
  float t = (1.f - e) / (1.f + e);
  return copysignf(t, x);
}
// LDS-only barrier: do NOT drain vmcnt (keeps prefetch loads / stores in flight).
__device__ __forceinline__ void lds_barrier(){
  asm volatile("s_waitcnt lgkmcnt(0)" ::: "memory");
  __builtin_amdgcn_s_barrier();
}

// ---------------- weight/emb conversion (f32 -> bf16, padded) ----------------
struct ConvJob { const float* s; uint16_t* d; int R, R0, C, Cp; };
struct ConvJobs { ConvJob j[12]; };

__global__ void k_convert(ConvJobs jobs){
  int stride = gridDim.x * blockDim.x;
  int tid0 = blockIdx.x * blockDim.x + threadIdx.x;
  for (int ji = 0; ji < 12; ++ji){
    const ConvJob jb = jobs.j[ji];
    int total = jb.R * jb.Cp;
    for (int i = tid0; i < total; i += stride){
      int r = i / jb.Cp, c = i - r*jb.Cp;
      float v = (r < jb.R0 && c < jb.C) ? jb.s[(size_t)r*jb.C + c] : 0.f;
      jb.d[i] = f2bf(v);
    }
  }
}

// ---------------- bf16 MFMA GEMM: global_load_lds staging, optional row-gather ----
// C[M,N] = A[M,K] @ W[Nb,K]^T + bias, 128x128 tile, BK=32, linear LDS.
// MODE 0: f32 out; 2: f32 out with t>=lens[n] row masking;
// MODE 3: bf16 out remapped to LSTM block layout [n/16][t][16][512] (N must be 512).
template<int MODE>
__global__ __launch_bounds__(256) void k_gemm(
    const uint16_t* __restrict__ A, const uint16_t* __restrict__ W,
    const float* __restrict__ bias, void* __restrict__ out,
    int N, int K, const int* __restrict__ lens, const int* __restrict__ tok)
{
  __shared__ __align__(16) uint16_t lsA[128][32];
  __shared__ __align__(16) uint16_t lsB[128][32];
  const int tid = threadIdx.x;
  const int n0 = blockIdx.x * 128, m0 = blockIdx.y * 128;
  const int l = tid & 63, w = tid >> 6;
  const int wm = (w >> 1) * 64, wn = (w & 1) * 64;
  const int fr = l & 15, fo = (l >> 4) * 8;
  const int srow = w*16 + (l >> 2);
  const int sce  = (l & 3) * 8;
  const int ar0 = m0 + srow, ar1 = m0 + 64 + srow;
  const size_t ab0 = (tok ? (size_t)tok[ar0] : (size_t)ar0) * K;
  const size_t ab1 = (tok ? (size_t)tok[ar1] : (size_t)ar1) * K;
  f32x4 acc[4][4] = {};
  for (int kt = 0; kt < K; kt += 32) {
    {
      __builtin_amdgcn_global_load_lds(
          (gas_u16)(A + ab0 + kt + sce),
          (las_u16)(&lsA[0][0] + w*512), 16, 0, 0);
      __builtin_amdgcn_global_load_lds(
          (gas_u16)(W + (size_t)(n0 + srow) * K + kt + sce),
          (las_u16)(&lsB[0][0] + w*512), 16, 0, 0);
      __builtin_amdgcn_global_load_lds(
          (gas_u16)(A + ab1 + kt + sce),
          (las_u16)(&lsA[0][0] + w*512 + 2048), 16, 0, 0);
      __builtin_amdgcn_global_load_lds(
          (gas_u16)(W + (size_t)(n0 + 64 + srow) * K + kt + sce),
          (las_u16)(&lsB[0][0] + w*512 + 2048), 16, 0, 0);
    }
    __syncthreads();
    short8 af[4], bfv[4];
    #pragma unroll
    for (int i = 0; i < 4; ++i) af[i]  = *(const short8*)(&lsA[wm + i*16 + fr][fo]);
    #pragma unroll
    for (int j = 0; j < 4; ++j) bfv[j] = *(const short8*)(&lsB[wn + j*16 + fr][fo]);
    #pragma unroll
    for (int i = 0; i < 4; ++i)
      #pragma unroll
      for (int j = 0; j < 4; ++j)
        acc[i][j] = __builtin_amdgcn_mfma_f32_16x16x32_bf16(af[i], bfv[j], acc[i][j], 0, 0, 0);
    __syncthreads();
  }
  const int r0 = (l >> 4) * 4, cc = l & 15;
  #pragma unroll
  for (int j = 0; j < 4; ++j) {
    int col = n0 + wn + j*16 + cc;
    if (col >= N) continue;
    float bv = bias[col];
    #pragma unroll
    for (int i = 0; i < 4; ++i) {
      #pragma unroll
      for (int r = 0; r < 4; ++r) {
        int row = m0 + wm + i*16 + r0 + r;
        float v = acc[i][j][r] + bv;
        if (MODE == 3) {
          int t = row & 63, n = row >> 6;
          size_t prow = ((size_t)(n >> 4)*64 + (size_t)t)*16 + (n & 15);
          ((uint16_t*)out)[prow * 512 + col] = f2bf(v);
        } else if (MODE == 2) {
          int t = row & 63, n = row >> 6;
          if (t >= lens[n]) v = 0.f;
          ((float*)out)[(size_t)row * N + col] = v;
        } else {
          ((float*)out)[(size_t)row * N + col] = v;
        }
      }
    }
  }
}

// ---------------- dual-group MFMA LSTM recurrence (per layer) ----------------
// Block = 32 samples in 2 independent groups of 16; 8 waves share one weight
// fragment set (64 VGPRs). Two groups' chains interleave -> latency hiding.
// t-loop unrolled by 2: static LDS buffer index, X prefetch distance 2.
template<int RB>
__device__ __forceinline__ void lstm_step(
    const short8 (&afr)[4][4],
    uint16_t (*hb)[2][16][136],          // [buf][grp][s][j]
    int s, int hi4, int j0, int t,
    const uint16_t* __restrict__ XA, const uint16_t* __restrict__ XB,
    uint2 (&xa)[4], uint2 (&xb)[4],
    f32x4& cstA, f32x4& cstB,
    uint16_t* __restrict__ hoA, uint16_t* __restrict__ hoB,
    float (&hfA)[4], float (&hfB)[4])
{
  short8 bA[4], bB[4];
  #pragma unroll
  for (int kk = 0; kk < 4; ++kk) {
    bA[kk] = *(const short8*)(&hb[RB][0][s][kk*32 + hi4*8]);
    bB[kk] = *(const short8*)(&hb[RB][1][s][kk*32 + hi4*8]);
  }
  f32x4 aA[4] = {{0,0,0,0},{0,0,0,0},{0,0,0,0},{0,0,0,0}};
  f32x4 aB[4] = {{0,0,0,0},{0,0,0,0},{0,0,0,0},{0,0,0,0}};
  #pragma unroll
  for (int kk = 0; kk < 4; ++kk) {
    #pragma unroll
    for (int g = 0; g < 4; ++g)
      aA[g] = __builtin_amdgcn_mfma_f32_16x16x32_bf16(afr[g][kk], bA[kk], aA[g], 0, 0, 0);
    #pragma unroll
    for (int g = 0; g < 4; ++g)
      aB[g] = __builtin_amdgcn_mfma_f32_16x16x32_bf16(afr[g][kk], bB[kk], aB[g], 0, 0, 0);
  }
  // ---- group A gates ----
  {
    uint16_t hv[4];
    #pragma unroll
    for (int r = 0; r < 4; ++r) {
      uint32_t wi = (r & 2) ? xa[0].y : xa[0].x;
      uint32_t wf = (r & 2) ? xa[1].y : xa[1].x;
      uint32_t wg = (r & 2) ? xa[2].y : xa[2].x;
      uint32_t wo = (r & 2) ? xa[3].y : xa[3].x;
      float zi = aA[0][r] + ((r & 1) ? bhi(wi) : blo(wi));
      float zf = aA[1][r] + ((r & 1) ? bhi(wf) : blo(wf));
      float zg = aA[2][r] + ((r & 1) ? bhi(wg) : blo(wg));
      float zo = aA[3][r] + ((r & 1) ? bhi(wo) : blo(wo));
      float cn = sigf(zf) * cstA[r] + sigf(zi) * ftanh(zg);
      float h  = sigf(zo) * ftanh(cn);
      cstA[r] = cn; hfA[r] = h; hv[r] = f2bf(h);
    }
    *(uint2*)(&hb[RB ^ 1][0][s][j0]) = *(const uint2*)hv;
    *(uint2*)(hoA + (size_t)t*HD) = *(const uint2*)hv;
    if (t + 2 < TT) {
      const uint16_t* Xn = XA + (size_t)(t+2)*8192;
      #pragma unroll
      for (int g = 0; g < 4; ++g) xa[g] = *(const uint2*)(Xn + g*128);
    }
  }
  // ---- group B gates ----
  {
    uint16_t hv[4];
    #pragma unroll
    for (int r = 0; r < 4; ++r) {
      uint32_t wi = (r & 2) ? xb[0].y : xb[0].x;
      uint32_t wf = (r & 2) ? xb[1].y : xb[1].x;
      uint32_t wg = (r & 2) ? xb[2].y : xb[2].x;
      uint32_t wo = (r & 2) ? xb[3].y : xb[3].x;
      float zi = aB[0][r] + ((r & 1) ? bhi(wi) : blo(wi));
      float zf = aB[1][r] + ((r & 1) ? bhi(wf) : blo(wf));
      float zg = aB[2][r] + ((r & 1) ? bhi(wg) : blo(wg));
      float zo = aB[3][r] + ((r & 1) ? bhi(wo) : blo(wo));
      float cn = sigf(zf) * cstB[r] + sigf(zi) * ftanh(zg);
      float h  = sigf(zo) * ftanh(cn);
      cstB[r] = cn; hfB[r] = h; hv[r] = f2bf(h);
    }
    *(uint2*)(&hb[RB ^ 1][1][s][j0]) = *(const uint2*)hv;
    *(uint2*)(hoB + (size_t)t*HD) = *(const uint2*)hv;
    if (t + 2 < TT) {
      const uint16_t* Xn = XB + (size_t)(t+2)*8192;
      #pragma unroll
      for (int g = 0; g < 4; ++g) xb[g] = *(const uint2*)(Xn + g*128);
    }
  }
  lds_barrier();
}

__global__ __launch_bounds__(512, 2) void k_lstm_d(
    const uint16_t* __restrict__ X,      // [NS/16][TT][16][512] bf16 = x@Wih^T + b
    const uint16_t* __restrict__ Whh,    // [512][128] bf16
    const float* __restrict__ h0i, const float* __restrict__ c0i,  // [NS][128] or null
    uint16_t* __restrict__ hout,         // [MT][128] bf16 (m = n*TT + t)
    float* __restrict__ hfin, float* __restrict__ cfin)            // [NS][128] or null
{
  __shared__ __align__(16) uint16_t hbuf[2][2][16][136];
  const int b = blockIdx.x;                     // 16 blocks, 32 samples each
  const int w = threadIdx.x >> 6, l = threadIdx.x & 63;
  const int s = l & 15, hi4 = l >> 4;
  const int j0 = w*16 + hi4*4;

  short8 afr[4][4];
  #pragma unroll
  for (int g = 0; g < 4; ++g)
    #pragma unroll
    for (int kk = 0; kk < 4; ++kk)
      afr[g][kk] = *(const short8*)(Whh + (size_t)(g*128 + w*16 + s)*128 + kk*32 + hi4*8);

  const int nA = b*32 + s, nB = b*32 + 16 + s;
  f32x4 cstA = {0,0,0,0}, cstB = {0,0,0,0};
  if (c0i) {
    cstA = *(const f32x4*)(c0i + (size_t)nA*128 + j0);
    cstB = *(const f32x4*)(c0i + (size_t)nB*128 + j0);
  }
  {
    uint16_t ha[4] = {0,0,0,0}, hc[4] = {0,0,0,0};
    if (h0i) {
      float4 v = *(const float4*)(h0i + (size_t)nA*128 + j0);
      ha[0]=f2bf(v.x); ha[1]=f2bf(v.y); ha[2]=f2bf(v.z); ha[3]=f2bf(v.w);
      float4 u = *(const float4*)(h0i + (size_t)nB*128 + j0);
      hc[0]=f2bf(u.x); hc[1]=f2bf(u.y); hc[2]=f2bf(u.z); hc[3]=f2bf(u.w);
    }
    *(uint2*)(&hbuf[0][0][s][j0]) = *(const uint2*)ha;
    *(uint2*)(&hbuf[0][1][s][j0]) = *(const uint2*)hc;
  }
  __syncthreads();

  const uint16_t* XA = X + (size_t)(2*b)*TT*8192 + (size_t)s*512 + j0;
  const uint16_t* XB = XA + (size_t)TT*8192;
  uint2 xA0[4], xA1[4], xB0[4], xB1[4];
  #pragma unroll
  for (int g = 0; g < 4; ++g) {
    xA0[g] = *(const uint2*)(XA + g*128);
    xA1[g] = *(const uint2*)(XA + 8192 + g*128);
    xB0[g] = *(const uint2*)(XB + g*128);
    xB1[g] = *(const uint2*)(XB + 8192 + g*128);
  }
  uint16_t* hoA = hout + (size_t)nA*TT*HD + j0;
  uint16_t* hoB = hout + (size_t)nB*TT*HD + j0;

  float hfA[4] = {0,0,0,0}, hfB[4] = {0,0,0,0};
  for (int t = 0; t < TT; t += 2) {
    lstm_step<0>(afr, hbuf, s, hi4, j0, t,   XA, XB, xA0, xB0, cstA, cstB, hoA, hoB, hfA, hfB);
    lstm_step<1>(afr, hbuf, s, hi4, j0, t+1, XA, XB, xA1, xB1, cstA, cstB, hoA, hoB, hfA, hfB);
  }
  if (hfin) {
    *(float4*)(hfin + (size_t)nA*128 + j0) = make_float4(hfA[0],hfA[1],hfA[2],hfA[3]);
    *(float4*)(hfin + (size_t)nB*128 + j0) = make_float4(hfB[0],hfB[1],hfB[2],hfB[3]);
    *(f32x4*)(cfin + (size_t)nA*128 + j0) = cstA;
    *(f32x4*)(cfin + (size_t)nB*128 + j0) = cstB;
  }
}

// ---------------- fused attention + feat assembly ----------------
__global__ __launch_bounds__(256) void k_attn(
    const float* __restrict__ keys,     // [MT][128] f32
    const uint16_t* __restrict__ h1,    // [MT][128] bf16
    const uint16_t* __restrict__ imgb,  // [512] bf16
    uint16_t* __restrict__ feat)        // [MT][896]
{
  __shared__ float ks[64][129];
  __shared__ float ps[4][64];
  const int n = blockIdx.x;
  for (int i = threadIdx.x; i < 64*128; i += 256)
    ks[i >> 7][i & 127] = keys[(size_t)n*8192 + i];
  const int w = threadIdx.x >> 6, l = threadIdx.x & 63;
  uint32_t hd = 0;
  if (n > 0) hd = ((const uint32_t*)(h1 + ((size_t)(n-1)*64 + 63)*128))[l];
  const uint4 iv = ((const uint4*)imgb)[l];
  __syncthreads();
  for (int tt = 0; tt < 16; ++tt) {
    const int t = tt*4 + w;
    const size_t m = (size_t)n*64 + t;
    const uint4* hp = (const uint4*)(h1 + m*128);
    float s = 0.f;
    #pragma unroll
    for (int k = 0; k < 16; ++k) {
      uint4 hv = hp[k];
      s += ks[l][8*k+0]*blo(hv.x) + ks[l][8*k+1]*bhi(hv.x)
         + ks[l][8*k+2]*blo(hv.y) + ks[l][8*k+3]*bhi(hv.y)
         + ks[l][8*k+4]*blo(hv.z) + ks[l][8*k+5]*bhi(hv.z)
         + ks[l][8*k+6]*blo(hv.w) + ks[l][8*k+7]*bhi(hv.w);
    }
    float mx = s;
    #pragma unroll
    for (int o = 32; o; o >>= 1) mx = fmaxf(mx, __shfl_xor(mx, o));
    float p = __expf(s - mx);
    float sm = p;
    #pragma unroll
    for (int o = 32; o; o >>= 1) sm += __shfl_xor(sm, o);
    p /= sm;
    ps[w][l] = p;
    float c0 = 0.f, c1 = 0.f;
    #pragma unroll
    for (int q = 0; q < 64; ++q) {
      float pq = ps[w][q];
      c0 += pq * ks[q][l];
      c1 += pq * ks[q][l + 64];
    }
    uint16_t* fr_ = feat + m*896;
    ((uint32_t*)fr_)[l] = ((const uint32_t*)(h1 + m*128))[l];  // h1 copy
    fr_[128 + l] = f2bf(c0);
    fr_[192 + l] = f2bf(c1);
    ((uint32_t*)(fr_ + 256))[l] = hd;                          // history
    ((uint4*)(fr_ + 384))[l] = iv;                             // img
  }
}

extern "C" void kernel_launch(void* const* d_in, const int* in_sizes, int n_in,
                              void* d_out, int out_size, void* d_ws, size_t ws_size,
                              hipStream_t stream) {
  const int*   questions = (const int*)d_in[0];
  const int*   answers   = (const int*)d_in[1];
  const int*   lens      = (const int*)d_in[2];
  const float* img       = (const float*)d_in[3];
  const float* emb       = (const float*)d_in[4];
  const float* eWih0 = (const float*)d_in[5],  *eWhh0 = (const float*)d_in[6],  *eB0 = (const float*)d_in[7];
  const float* eWih1 = (const float*)d_in[8],  *eWhh1 = (const float*)d_in[9],  *eB1 = (const float*)d_in[10];
  const float* dWih0 = (const float*)d_in[11], *dWhh0 = (const float*)d_in[12], *dB0 = (const float*)d_in[13];
  const float* dWih1 = (const float*)d_in[14], *dWhh1 = (const float*)d_in[15], *dB1 = (const float*)d_in[16];
  const float* Wk   = (const float*)d_in[17], *bk   = (const float*)d_in[18];
  const float* Wout = (const float*)d_in[19], *bout = (const float*)d_in[20];

  char* ws = (char*)d_ws;
  size_t off = 0;
  auto alloc = [&](size_t n)->char* {
    char* p = ws + off; off += (n + 255) & ~(size_t)255; return p;
  };
  uint16_t* embP  = (uint16_t*)alloc((size_t)VD*128*2);
  uint16_t* wih0e = (uint16_t*)alloc(512*128*2);
  uint16_t* whh0e = (uint16_t*)alloc(512*128*2);
  uint16_t* wih1e = (uint16_t*)alloc(512*128*2);
  uint16_t* whh1e = (uint16_t*)alloc(512*128*2);
  uint16_t* wih0d = (uint16_t*)alloc(512*128*2);
  uint16_t* whh0d = (uint16_t*)alloc(512*128*2);
  uint16_t* wih1d = (uint16_t*)alloc(512*128*2);
  uint16_t* whh1d = (uint16_t*)alloc(512*128*2);
  uint16_t* wkb   = (uint16_t*)alloc(128*128*2);
  uint16_t* woutb = (uint16_t*)alloc((size_t)1024*896*2);   // padded to 1024 rows
  uint16_t* imgb  = (uint16_t*)alloc(512*2);
  uint16_t* Xbuf  = (uint16_t*)alloc((size_t)MT*512*2);
  uint16_t* hA    = (uint16_t*)alloc((size_t)MT*128*2);
  uint16_t* h1b   = (uint16_t*)alloc((size_t)MT*128*2);
  float*    keysf = (float*)   alloc((size_t)MT*128*4);
  uint16_t* feat  = (uint16_t*)alloc((size_t)MT*896*2);
  float* eh0 = (float*)alloc(NS*128*4);
  float* ec0 = (float*)alloc(NS*128*4);
  float* eh1 = (float*)alloc(NS*128*4);
  float* ec1 = (float*)alloc(NS*128*4);
  if (off > ws_size) return;  // workspace too small; fail visibly

  ConvJobs jobs;
  jobs.j[0]  = {emb,   embP,  VD,  VD,  ED,  128};
  jobs.j[1]  = {eWih0, wih0e, 512, 512, ED,  128};
  jobs.j[2]  = {eWhh0, whh0e, 512, 512, 128, 128};
  jobs.j[3]  = {eWih1, wih1e, 512, 512, 128, 128};
  jobs.j[4]  = {eWhh1, whh1e, 512, 512, 128, 128};
  jobs.j[5]  = {dWih0, wih0d, 512, 512, ED,  128};
  jobs.j[6]  = {dWhh0, whh0d, 512, 512, 128, 128};
  jobs.j[7]  = {dWih1, wih1d, 512, 512, 128, 128};
  jobs.j[8]  = {dWhh1, whh1d, 512, 512, 128, 128};
  jobs.j[9]  = {Wk,    wkb,   128, 128, 128, 128};
  jobs.j[10] = {Wout,  woutb, 1024, VD, 896, 896};
  jobs.j[11] = {img,   imgb,  1,   1,   512, 512};
  hipLaunchKernelGGL(k_convert, dim3(1024), dim3(256), 0, stream, jobs);

  // ---- encoder ----
  hipLaunchKernelGGL(k_gemm<3>, dim3(4, MT/128), dim3(256), 0, stream, embP, wih0e, eB0, Xbuf, 512, 128, nullptr, questions);
  hipLaunchKernelGGL(k_lstm_d, dim3(NS/32), dim3(512), 0, stream, Xbuf, whh0e,
                     (const float*)nullptr, (const float*)nullptr, hA, eh0, ec0);
  hipLaunchKernelGGL(k_gemm<3>, dim3(4, MT/128), dim3(256), 0, stream, hA, wih1e, eB1, Xbuf, 512, 128, nullptr, nullptr);
  hipLaunchKernelGGL(k_lstm_d, dim3(NS/32), dim3(512), 0, stream, Xbuf, whh1e,
                     (const float*)nullptr, (const float*)nullptr, h1b, eh1, ec1);
  hipLaunchKernelGGL(k_gemm<0>, dim3(1, MT/128), dim3(256), 0, stream, h1b, wkb, bk, keysf, 128, 128, nullptr, nullptr);

  // ---- decoder ----
  hipLaunchKernelGGL(k_gemm<3>, dim3(4, MT/128), dim3(256), 0, stream, embP, wih0d, dB0, Xbuf, 512, 128, nullptr, answers);
  hipLaunchKernelGGL(k_lstm_d, dim3(NS/32), dim3(512), 0, stream, Xbuf, whh0d,
                     eh0, ec0, hA, (float*)nullptr, (float*)nullptr);
  hipLaunchKernelGGL(k_gemm<3>, dim3(4, MT/128), dim3(256), 0, stream, hA, wih1d, dB1, Xbuf, 512, 128, nullptr, nullptr);
  hipLaunchKernelGGL(k_lstm_d, dim3(NS/32), dim3(512), 0, stream, Xbuf, whh1d,
                     eh1, ec1, h1b, (float*)nullptr, (float*)nullptr);

  // ---- fused attention/feat + output projection ----
  hipLaunchKernelGGL(k_attn, dim3(NS), dim3(256), 0, stream, keysf, h1b, imgb, feat);
  hipLaunchKernelGGL(k_gemm<2>, dim3(8, MT/128), dim3(256), 0, stream, feat, woutb, bout, d_out, VD, 896, lens, nullptr);
}